// Round 6
// baseline (1988.812 us; speedup 1.0000x reference)
//
#include <hip/hip_runtime.h>
#include <hip/hip_bf16.h>
#include <math.h>

// Problem constants
#define BB     256
#define NMEL   80
#define TMEL   800
#define NFR    16          // frames per step
#define TT     50          // decoder steps
#define RNN    1024
#define ENC    256
#define INDIM  1280        // RNN + ENC == MEL_DIM
#define G4     4096        // 4*RNN
#define MROWS  (TT*BB)     // 12800

typedef __attribute__((ext_vector_type(8))) short bf16x8;
typedef __attribute__((ext_vector_type(4))) float f32x4;

#define GAS __attribute__((address_space(1)))
#define LAS __attribute__((address_space(3)))

__device__ __forceinline__ unsigned short f2bf(float f) {
    unsigned int u = __float_as_uint(f);
    u += 0x7FFFu + ((u >> 16) & 1u);     // round-to-nearest-even
    return (unsigned short)(u >> 16);
}
__device__ __forceinline__ float bf2f(unsigned short s) {
    return __uint_as_float(((unsigned int)s) << 16);
}

// ---------------- prep kernels ----------------

__global__ void k_f32_to_bf16(const float* __restrict__ src,
                              unsigned short* __restrict__ dst, int n) {
    for (int i = blockIdx.x * blockDim.x + threadIdx.x; i < n;
         i += gridDim.x * blockDim.x)
        dst[i] = f2bf(src[i]);
}

// W_proj[:, 0:1024] -> bf16, N-permuted: dst row m' = mel*16+fr comes from
// W_proj row m = fr*80+mel. Makes mel-GEMM output contiguous along (t,fr).
__global__ void k_conv_wph(const float* __restrict__ wproj,
                           unsigned short* __restrict__ dst) {
    const int n = INDIM * RNN;
    for (int i = blockIdx.x * blockDim.x + threadIdx.x; i < n;
         i += gridDim.x * blockDim.x) {
        int mp = i >> 10, k = i & 1023;
        int mel = mp >> 4, fr = mp & 15;
        dst[i] = f2bf(wproj[(fr * NMEL + mel) * INDIM + k]);
    }
}

// teacher-forced inputs: frames[t][b][k] = (t==0)?0:target[b][k%80][t*16+k/80]
__global__ void k_frames(const float* __restrict__ target,
                         unsigned short* __restrict__ frames) {
    const int n = TT * BB * INDIM;
    for (int i = blockIdx.x * blockDim.x + threadIdx.x; i < n;
         i += gridDim.x * blockDim.x) {
        int k = i % INDIM;
        int rb = i / INDIM;
        int b = rb & (BB - 1);
        int t = rb >> 8;
        unsigned short v = 0;
        if (t > 0) {
            int mel = k % NMEL, fr = k / NMEL;
            v = f2bf(target[(b * NMEL + mel) * TMEL + t * NFR + fr]);
        }
        frames[i] = v;
    }
}

// ctxproj[b][m'] = b_proj[m] + context[b]·W_proj[m][1024:1280], m'=mel*16+fr,
// m = fr*80+mel (same permutation as k_conv_wph).
__global__ void k_ctxproj(const float* __restrict__ context,
                          const float* __restrict__ wproj,
                          const float* __restrict__ bproj,
                          float* __restrict__ ctx) {
    int i = blockIdx.x * blockDim.x + threadIdx.x;
    if (i >= BB * INDIM) return;
    int mp = i % INDIM, b = i / INDIM;
    int mel = mp >> 4, fr = mp & 15;
    int m = fr * NMEL + mel;
    const float* wr = wproj + (size_t)m * INDIM + RNN;
    const float* cb = context + b * ENC;
    float acc = bproj[m];
    for (int e = 0; e < ENC; ++e) acc += cb[e] * wr[e];
    ctx[(size_t)b * INDIM + mp] = acc;
}

// gatectx[b] = b_gate + context[b]·W_gate[0][1024:1280]
__global__ void k_gatectx(const float* __restrict__ context,
                          const float* __restrict__ wgate,
                          const float* __restrict__ bgate,
                          float* __restrict__ gctx) {
    int b = blockIdx.x * blockDim.x + threadIdx.x;
    if (b >= BB) return;
    float acc = bgate[0];
    const float* cb = context + b * ENC;
    for (int e = 0; e < ENC; ++e) acc += cb[e] * wgate[RNN + e];
    gctx[b] = acc;
}

// ---------------- m97-structure tile GEMM core ----------------
// 128x128 WG tile, BK=32, 4 waves of 64x64, global_load_lds(16B) staging,
// 2-barrier K loop. A [M][STRIDE], Bw [N][STRIDE] (row-major, C = A@Bw^T).
template<int STRIDE, int KDIM>
__device__ __forceinline__ void gemm_core(const unsigned short* __restrict__ A,
                                          const unsigned short* __restrict__ Bw,
                                          int mblk, int nblk,
                                          unsigned short* As, unsigned short* Bs,
                                          f32x4 acc[4][4]) {
    const int tid = threadIdx.x, lane = tid & 63, wid = tid >> 6;
    const int wm = (wid >> 1) * 64, wn = (wid & 1) * 64;
    const int lr = lane & 15, lko = (lane >> 4) * 8;
    const int c0 = wid * 128 + lane;          // call 0 chunk for this lane
    const int c1 = c0 + 64;                   // call 1
    const int r0 = c0 >> 2, o0 = (c0 & 3) * 8;
    const int r1 = c1 >> 2, o1 = (c1 & 3) * 8;
    const unsigned short* a0p = A + (size_t)(mblk + r0) * STRIDE + o0;
    const unsigned short* a1p = A + (size_t)(mblk + r1) * STRIDE + o1;
    const unsigned short* b0p = Bw + (size_t)(nblk + r0) * STRIDE + o0;
    const unsigned short* b1p = Bw + (size_t)(nblk + r1) * STRIDE + o1;
    unsigned short* da0 = As + wid * 1024;          // uniform per wave
    unsigned short* da1 = As + wid * 1024 + 512;
    unsigned short* db0 = Bs + wid * 1024;
    unsigned short* db1 = Bs + wid * 1024 + 512;
    for (int k0 = 0; k0 < KDIM; k0 += 32) {
        __syncthreads();   // previous compute done before LDS overwrite
        __builtin_amdgcn_global_load_lds((const GAS unsigned int*)(a0p + k0),
                                         (LAS unsigned int*)da0, 16, 0, 0);
        __builtin_amdgcn_global_load_lds((const GAS unsigned int*)(a1p + k0),
                                         (LAS unsigned int*)da1, 16, 0, 0);
        __builtin_amdgcn_global_load_lds((const GAS unsigned int*)(b0p + k0),
                                         (LAS unsigned int*)db0, 16, 0, 0);
        __builtin_amdgcn_global_load_lds((const GAS unsigned int*)(b1p + k0),
                                         (LAS unsigned int*)db1, 16, 0, 0);
        __syncthreads();   // compiler drains vmcnt before barrier
        bf16x8 af[4], bfv[4];
        #pragma unroll
        for (int mi = 0; mi < 4; ++mi)
            af[mi] = *(const bf16x8*)(As + (wm + mi * 16 + lr) * 32 + lko);
        #pragma unroll
        for (int ni = 0; ni < 4; ++ni)
            bfv[ni] = *(const bf16x8*)(Bs + (wn + ni * 16 + lr) * 32 + lko);
        #pragma unroll
        for (int mi = 0; mi < 4; ++mi)
            #pragma unroll
            for (int ni = 0; ni < 4; ++ni)
                acc[mi][ni] = __builtin_amdgcn_mfma_f32_16x16x32_bf16(
                    af[mi], bfv[ni], acc[mi][ni], 0, 0, 0);
    }
}

// T1 bijective XCD swizzle (nwg % 8 == 0 for both GEMM grids)
__device__ __forceinline__ void swz_grid(int& sx, int& sy) {
    const int nwg = gridDim.x * gridDim.y;
    const int id = blockIdx.y * gridDim.x + blockIdx.x;
    const int s = (id & 7) * (nwg >> 3) + (id >> 3);
    sx = s % gridDim.x;
    sy = s / gridDim.x;
}

// GEMM 1: xproj = frames @ W_ih^T + b_ih + b_hh (bf16 out). M=12800 N=4096 K=1280
__global__ __launch_bounds__(256) void k_gemm_xproj(
    const unsigned short* __restrict__ A,   // [12800][1280]
    const unsigned short* __restrict__ Bw,  // [4096][1280]
    const float* __restrict__ b_ih, const float* __restrict__ b_hh,
    unsigned short* __restrict__ Cout)      // [12800][4096]
{
    __shared__ unsigned short As[4096], Bs[4096];
    f32x4 acc[4][4] = {};
    int sx, sy; swz_grid(sx, sy);
    const int mblk = sy * 128, nblk = sx * 128;
    gemm_core<INDIM, INDIM>(A, Bw, mblk, nblk, As, Bs, acc);
    const int lane = threadIdx.x & 63, wid = threadIdx.x >> 6;
    const int wm = (wid >> 1) * 64, wn = (wid & 1) * 64, lr = lane & 15;
    #pragma unroll
    for (int ni = 0; ni < 4; ++ni) {
        const int col = nblk + wn + ni * 16 + lr;
        const float bias = b_ih[col] + b_hh[col];
        #pragma unroll
        for (int mi = 0; mi < 4; ++mi) {
            const int row0 = mblk + wm + mi * 16 + (lane >> 4) * 4;
            #pragma unroll
            for (int r = 0; r < 4; ++r)
                Cout[(size_t)(row0 + r) * G4 + col] = f2bf(acc[mi][ni][r] + bias);
        }
    }
}

// GEMM 2: mel = h_all[1:] @ Wp'^T + ctxproj', coalesced scatter via LDS
// transpose. M=12800, N=1280 (permuted col' = mel*16+fr), K=1024.
__global__ __launch_bounds__(256) void k_gemm_mel(
    const unsigned short* __restrict__ A,   // [12800][1024]
    const unsigned short* __restrict__ Bw,  // Wp' [1280][1024] (permuted)
    const float* __restrict__ ctxproj,      // [256][1280] (permuted)
    float* __restrict__ out0)               // [256][80][800]
{
    __shared__ unsigned short As[4096], Bs[4096];
    __shared__ float txp[4][16][20];        // per-wave transpose; 20: align+banks
    f32x4 acc[4][4] = {};
    int sx, sy; swz_grid(sx, sy);
    const int mblk = sy * 128, nblk = sx * 128;
    gemm_core<RNN, RNN>(A, Bw, mblk, nblk, As, Bs, acc);
    const int lane = threadIdx.x & 63, wid = threadIdx.x >> 6;
    const int wm = (wid >> 1) * 64, wn = (wid & 1) * 64, lr = lane & 15;
    const int rbase = (lane >> 4) * 4;
    const int rowl = lane & 15, fq = lane >> 4;   // readback roles
    #pragma unroll
    for (int mi = 0; mi < 4; ++mi) {
        const int row0 = mblk + wm + mi * 16;     // 16 rows: same t, b0..b0+15
        const int t = row0 >> 8, b0 = row0 & 255;
        #pragma unroll
        for (int ni = 0; ni < 4; ++ni) {
            const int colbase = nblk + wn + ni * 16;  // one mel, fr 0..15
            const int mel = colbase >> 4;
            __syncthreads();                      // txp free for reuse
            #pragma unroll
            for (int r = 0; r < 4; ++r)
                txp[wid][rbase + r][lr] = acc[mi][ni][r];
            __syncthreads();                      // transpose visible
            const int bL = b0 + rowl;
            f32x4 v = *(const f32x4*)&txp[wid][rowl][fq * 4];
            f32x4 cx = *(const f32x4*)(ctxproj + (size_t)bL * INDIM +
                                       mel * 16 + fq * 4);
            *(f32x4*)(out0 + (size_t)(bL * NMEL + mel) * TMEL +
                      t * NFR + fq * 4) = v + cx;
        }
    }
}

// ---------------- per-step fused LSTM kernel (v5) ----------------
// gates = xproj[t] + h_prev @ Whh^T ; LSTM ; h_next(bf16), c(f32).
// Grid (64, 4): n0 = bx*16 (16 cols per gate), m0 = by*64 (batch rows).
// 512 thr = 8 waves = (kh in 0..3 K-slice of 256) x (mh in 0..1 m-half of 32).
// Each wave: 2 m-frags x 4 vcol-frags (= 4 gates x 16 cols), K-partials
// reduced via LDS atomicAdd at the end.
// A (h_prev) fragments load DIRECT to registers (same coalescing as staging),
// prefetched 1 iter ahead. B (Whh) double-buffered in LDS via global_load_lds
// with COUNTED vmcnt(4) + raw s_barrier (no vmcnt(0) drain in the loop):
// tile t+1's {2 gload_lds + 2 A-reg loads} stay in flight across barriers.
__global__ __launch_bounds__(512) void k_step(
    const unsigned short* __restrict__ Whh,     // [4096][1024] bf16
    const unsigned short* __restrict__ xproj_t, // [256][4096] bf16
    const unsigned short* __restrict__ h_prev,  // [256][1024] bf16
    unsigned short* __restrict__ h_next,        // [256][1024] bf16
    float* __restrict__ c)                      // [256][1024] f32
{
    __shared__ unsigned short Bsm[2][8192];     // [buf][kh 4][vr 64][k 32] 16KBx2
    __shared__ float gates[4][64][20];          // [gate][row][16 cols + pad] 20KB
    const int tid = threadIdx.x, lane = tid & 63, w = tid >> 6;
    const int kh = w & 3, mh = w >> 2;
    const int n0 = blockIdx.x * 16, m0 = blockIdx.y * 64;
    const int lr = lane & 15, q = lane >> 4;

    // B staging descriptors: chunk c -> kh=c>>8, vr=(c>>2)&63, s=c&3
    // vr: gate = vr>>4, col = n0 + (vr&15). 2 calls/wave cover 1024 chunks.
    const int c0 = w * 64 + lane, c1 = c0 + 512;
    const int k0h = c0 >> 8, vr0 = (c0 >> 2) & 63, s0 = c0 & 3;
    const int k1h = c1 >> 8, vr1 = (c1 >> 2) & 63, s1 = c1 & 3;
    const unsigned short* b0s = Whh +
        (size_t)((vr0 >> 4) * RNN + n0 + (vr0 & 15)) * RNN + k0h * 256 + s0 * 8;
    const unsigned short* b1s = Whh +
        (size_t)((vr1 >> 4) * RNN + n0 + (vr1 & 15)) * RNN + k1h * 256 + s1 * 8;
    const int bd0 = w * 512;                    // wave-uniform LDS short offsets
    const int bd1 = w * 512 + 4096;

    // A direct-to-reg fragment sources (16 rows x 64B contiguous per wave)
    const unsigned short* aS0 = h_prev + (size_t)(m0 + mh * 32 + lr) * RNN +
                                kh * 256 + q * 8;
    const unsigned short* aS1 = aS0 + (size_t)16 * RNN;

    // stage B(0) into buf 0
    __builtin_amdgcn_global_load_lds((const GAS unsigned int*)b0s,
        (LAS unsigned int*)&Bsm[0][bd0], 16, 0, 0);
    __builtin_amdgcn_global_load_lds((const GAS unsigned int*)b1s,
        (LAS unsigned int*)&Bsm[0][bd1], 16, 0, 0);
    // A(0)
    bf16x8 a0 = *(const bf16x8*)aS0;
    bf16x8 a1 = *(const bf16x8*)aS1;
    // phase 0: gates := xproj tile (flies under stage-0)
    {
        const int g = tid >> 7, row = (tid >> 1) & 63, half = tid & 1;
        bf16x8 xv = *(const bf16x8*)(xproj_t + (size_t)(m0 + row) * G4 +
                                     g * RNN + n0 + half * 8);
        #pragma unroll
        for (int j = 0; j < 8; ++j)
            gates[g][row][half * 8 + j] = bf2f((unsigned short)xv[j]);
    }

    f32x4 acc[2][4] = {};
    #pragma unroll
    for (int t = 0; t < 8; ++t) {
        bf16x8 na0, na1;
        if (t < 7) {
            __builtin_amdgcn_global_load_lds(
                (const GAS unsigned int*)(b0s + (t + 1) * 32),
                (LAS unsigned int*)&Bsm[(t + 1) & 1][bd0], 16, 0, 0);
            __builtin_amdgcn_global_load_lds(
                (const GAS unsigned int*)(b1s + (t + 1) * 32),
                (LAS unsigned int*)&Bsm[(t + 1) & 1][bd1], 16, 0, 0);
            na0 = *(const bf16x8*)(aS0 + (t + 1) * 32);
            na1 = *(const bf16x8*)(aS1 + (t + 1) * 32);
        }
        // tile-t complete; allow tile-t+1's 4 VMEM ops to stay in flight
        if (t < 7) asm volatile("s_waitcnt vmcnt(4)" ::: "memory");
        else       asm volatile("s_waitcnt vmcnt(0)" ::: "memory");
        asm volatile("s_barrier" ::: "memory");
        __builtin_amdgcn_sched_barrier(0);
        const unsigned short* Bb = &Bsm[t & 1][kh * 2048];
        bf16x8 bv0 = *(const bf16x8*)(Bb + (0 * 16 + lr) * 32 + q * 8);
        bf16x8 bv1 = *(const bf16x8*)(Bb + (1 * 16 + lr) * 32 + q * 8);
        bf16x8 bv2 = *(const bf16x8*)(Bb + (2 * 16 + lr) * 32 + q * 8);
        bf16x8 bv3 = *(const bf16x8*)(Bb + (3 * 16 + lr) * 32 + q * 8);
        acc[0][0] = __builtin_amdgcn_mfma_f32_16x16x32_bf16(a0, bv0, acc[0][0], 0, 0, 0);
        acc[1][0] = __builtin_amdgcn_mfma_f32_16x16x32_bf16(a1, bv0, acc[1][0], 0, 0, 0);
        acc[0][1] = __builtin_amdgcn_mfma_f32_16x16x32_bf16(a0, bv1, acc[0][1], 0, 0, 0);
        acc[1][1] = __builtin_amdgcn_mfma_f32_16x16x32_bf16(a1, bv1, acc[1][1], 0, 0, 0);
        acc[0][2] = __builtin_amdgcn_mfma_f32_16x16x32_bf16(a0, bv2, acc[0][2], 0, 0, 0);
        acc[1][2] = __builtin_amdgcn_mfma_f32_16x16x32_bf16(a1, bv2, acc[1][2], 0, 0, 0);
        acc[0][3] = __builtin_amdgcn_mfma_f32_16x16x32_bf16(a0, bv3, acc[0][3], 0, 0, 0);
        acc[1][3] = __builtin_amdgcn_mfma_f32_16x16x32_bf16(a1, bv3, acc[1][3], 0, 0, 0);
        // all my ds_reads retired before signaling buffer-free
        asm volatile("s_waitcnt lgkmcnt(0)" ::: "memory");
        asm volatile("s_barrier" ::: "memory");
        if (t < 7) { a0 = na0; a1 = na1; }
    }

    // K-partial reduction into gates (4 kh-waves contend per address)
    #pragma unroll
    for (int mi = 0; mi < 2; ++mi)
        #pragma unroll
        for (int ni = 0; ni < 4; ++ni)
            #pragma unroll
            for (int r = 0; r < 4; ++r)
                atomicAdd(&gates[ni][mh * 32 + mi * 16 + q * 4 + r][lr],
                          acc[mi][ni][r]);
    __syncthreads();   // full drain fine here (loop done)

    // LSTM elementwise over 64x16 outputs; c f32 global
    #pragma unroll
    for (int q2 = 0; q2 < 2; ++q2) {
        const int e = tid + q2 * 512;
        const int row = e >> 4, col = e & 15;
        const int b = m0 + row, j = n0 + col;
        const float xi = gates[0][row][col];
        const float xf = gates[1][row][col];
        const float xg = gates[2][row][col];
        const float xo = gates[3][row][col];
        const float si = 1.f / (1.f + expf(-xi));
        const float sf = 1.f / (1.f + expf(-xf));
        const float so = 1.f / (1.f + expf(-xo));
        const float cp = c[(size_t)b * RNN + j];
        const float cn = sf * cp + si * tanhf(xg);
        const float hn = so * tanhf(cn);
        c[(size_t)b * RNN + j] = cn;
        h_next[(size_t)b * RNN + j] = f2bf(hn);
    }
}

// gate[b*50+t] = gatectx[b] + h_all[t+1][b]·w_gate[0:1024] ; one wave per row
__global__ void k_gate(const unsigned short* __restrict__ h,  // [12800][1024]
                       const float* __restrict__ wgate,
                       const float* __restrict__ gctx,
                       float* __restrict__ out1) {
    const int gw = (blockIdx.x * blockDim.x + threadIdx.x) >> 6;
    const int lane = threadIdx.x & 63;
    if (gw >= MROWS) return;
    const unsigned short* hr = h + (size_t)gw * RNN + lane * 16;
    const float* wr = wgate + lane * 16;
    float acc = 0.f;
    #pragma unroll
    for (int j = 0; j < 16; ++j) acc += bf2f(hr[j]) * wr[j];
    for (int off = 32; off; off >>= 1) acc += __shfl_down(acc, off);
    if (lane == 0) {
        const int t = gw >> 8, b = gw & 255;
        out1[b * TT + t] = acc + gctx[b];
    }
}

// ---------------- workspace layout (all offsets 1KB-aligned) ----------------
static const size_t OFF_WIH   = 0;                                    // 10.5 MB
static const size_t OFF_WHH   = OFF_WIH   + (size_t)G4 * INDIM * 2;   // 8 MB
static const size_t OFF_WPH   = OFF_WHH   + (size_t)G4 * RNN * 2;     // 2.6 MB
static const size_t OFF_FRM   = OFF_WPH   + (size_t)INDIM * RNN * 2;  // 32.8 MB
static const size_t OFF_XPROJ = OFF_FRM   + (size_t)MROWS * INDIM * 2;// 104.9 MB
static const size_t OFF_HALL  = OFF_XPROJ + (size_t)MROWS * G4 * 2;   // 26.7 MB
static const size_t OFF_C     = OFF_HALL  + (size_t)(TT + 1) * BB * RNN * 2;
static const size_t OFF_CTX   = OFF_C     + (size_t)BB * RNN * 4;
static const size_t OFF_GCTX  = OFF_CTX   + (size_t)BB * INDIM * 4;

extern "C" void kernel_launch(void* const* d_in, const int* in_sizes, int n_in,
                              void* d_out, int out_size, void* d_ws, size_t ws_size,
                              hipStream_t stream) {
    const float* context = (const float*)d_in[0];
    const float* target  = (const float*)d_in[1];
    const float* W_ih    = (const float*)d_in[2];
    const float* b_ih    = (const float*)d_in[3];
    const float* W_hh    = (const float*)d_in[4];
    const float* b_hh    = (const float*)d_in[5];
    const float* W_proj  = (const float*)d_in[6];
    const float* b_proj  = (const float*)d_in[7];
    const float* W_gate  = (const float*)d_in[8];
    const float* b_gate  = (const float*)d_in[9];
    float* out = (float*)d_out;
    char* ws = (char*)d_ws;

    unsigned short* wih_bf  = (unsigned short*)(ws + OFF_WIH);
    unsigned short* whh_bf  = (unsigned short*)(ws + OFF_WHH);
    unsigned short* wph_bf  = (unsigned short*)(ws + OFF_WPH);
    unsigned short* frames  = (unsigned short*)(ws + OFF_FRM);
    unsigned short* xproj   = (unsigned short*)(ws + OFF_XPROJ);
    unsigned short* h_all   = (unsigned short*)(ws + OFF_HALL);
    float*          c_buf   = (float*)(ws + OFF_C);
    float*          ctxproj = (float*)(ws + OFF_CTX);
    float*          gctx    = (float*)(ws + OFF_GCTX);

    // per-call init (harness does not re-zero ws between replays)
    hipMemsetAsync(h_all, 0, (size_t)BB * RNN * 2, stream);   // h0 slot
    hipMemsetAsync(c_buf, 0, (size_t)BB * RNN * 4, stream);   // c0

    k_f32_to_bf16<<<2048, 256, 0, stream>>>(W_ih, wih_bf, G4 * INDIM);
    k_f32_to_bf16<<<2048, 256, 0, stream>>>(W_hh, whh_bf, G4 * RNN);
    k_conv_wph<<<2048, 256, 0, stream>>>(W_proj, wph_bf);
    k_frames<<<2048, 256, 0, stream>>>(target, frames);
    k_ctxproj<<<(BB * INDIM + 255) / 256, 256, 0, stream>>>(context, W_proj,
                                                            b_proj, ctxproj);
    k_gatectx<<<1, 256, 0, stream>>>(context, W_gate, b_gate, gctx);

    k_gemm_xproj<<<dim3(G4 / 128, MROWS / 128), 256, 0, stream>>>(
        frames, wih_bf, b_ih, b_hh, xproj);

    for (int t = 0; t < TT; ++t) {
        k_step<<<dim3(64, 4), 512, 0, stream>>>(
            whh_bf, xproj + (size_t)t * BB * G4,
            h_all + (size_t)t * BB * RNN,
            h_all + (size_t)(t + 1) * BB * RNN, c_buf);
    }

    k_gemm_mel<<<dim3(INDIM / 128, MROWS / 128), 256, 0, stream>>>(
        h_all + (size_t)BB * RNN, wph_bf, ctxproj, out);
    k_gate<<<MROWS / 4, 256, 0, stream>>>(h_all + (size_t)BB * RNN, W_gate,
                                          gctx, out + (size_t)BB * NMEL * TMEL);
}

// Round 7
// 1210.785 us; speedup vs baseline: 1.6426x; 1.6426x over previous
//
#include <hip/hip_runtime.h>
#include <hip/hip_bf16.h>
#include <math.h>

// Problem constants
#define BB     256
#define NMEL   80
#define TMEL   800
#define NFR    16          // frames per step
#define TT     50          // decoder steps
#define RNN    1024
#define ENC    256
#define INDIM  1280        // RNN + ENC == MEL_DIM
#define G4     4096        // 4*RNN
#define MROWS  (TT*BB)     // 12800

typedef __attribute__((ext_vector_type(8))) short bf16x8;
typedef __attribute__((ext_vector_type(4))) float f32x4;

#define GAS __attribute__((address_space(1)))
#define LAS __attribute__((address_space(3)))

__device__ __forceinline__ unsigned short f2bf(float f) {
    unsigned int u = __float_as_uint(f);
    u += 0x7FFFu + ((u >> 16) & 1u);     // round-to-nearest-even
    return (unsigned short)(u >> 16);
}
__device__ __forceinline__ float bf2f(unsigned short s) {
    return __uint_as_float(((unsigned int)s) << 16);
}

// ---------------- prep kernels ----------------

__global__ void k_f32_to_bf16(const float* __restrict__ src,
                              unsigned short* __restrict__ dst, int n) {
    for (int i = blockIdx.x * blockDim.x + threadIdx.x; i < n;
         i += gridDim.x * blockDim.x)
        dst[i] = f2bf(src[i]);
}

// W_proj[:, 0:1024] -> bf16, N-permuted: dst row m' = mel*16+fr comes from
// W_proj row m = fr*80+mel. Makes mel-GEMM output contiguous along (t,fr).
__global__ void k_conv_wph(const float* __restrict__ wproj,
                           unsigned short* __restrict__ dst) {
    const int n = INDIM * RNN;
    for (int i = blockIdx.x * blockDim.x + threadIdx.x; i < n;
         i += gridDim.x * blockDim.x) {
        int mp = i >> 10, k = i & 1023;
        int mel = mp >> 4, fr = mp & 15;
        dst[i] = f2bf(wproj[(fr * NMEL + mel) * INDIM + k]);
    }
}

// teacher-forced inputs: frames[t][b][k] = (t==0)?0:target[b][k%80][t*16+k/80]
__global__ void k_frames(const float* __restrict__ target,
                         unsigned short* __restrict__ frames) {
    const int n = TT * BB * INDIM;
    for (int i = blockIdx.x * blockDim.x + threadIdx.x; i < n;
         i += gridDim.x * blockDim.x) {
        int k = i % INDIM;
        int rb = i / INDIM;
        int b = rb & (BB - 1);
        int t = rb >> 8;
        unsigned short v = 0;
        if (t > 0) {
            int mel = k % NMEL, fr = k / NMEL;
            v = f2bf(target[(b * NMEL + mel) * TMEL + t * NFR + fr]);
        }
        frames[i] = v;
    }
}

// ctxproj[b][m'] = b_proj[m] + context[b]·W_proj[m][1024:1280], m'=mel*16+fr,
// m = fr*80+mel (same permutation as k_conv_wph).
__global__ void k_ctxproj(const float* __restrict__ context,
                          const float* __restrict__ wproj,
                          const float* __restrict__ bproj,
                          float* __restrict__ ctx) {
    int i = blockIdx.x * blockDim.x + threadIdx.x;
    if (i >= BB * INDIM) return;
    int mp = i % INDIM, b = i / INDIM;
    int mel = mp >> 4, fr = mp & 15;
    int m = fr * NMEL + mel;
    const float* wr = wproj + (size_t)m * INDIM + RNN;
    const float* cb = context + b * ENC;
    float acc = bproj[m];
    for (int e = 0; e < ENC; ++e) acc += cb[e] * wr[e];
    ctx[(size_t)b * INDIM + mp] = acc;
}

// gatectx[b] = b_gate + context[b]·W_gate[0][1024:1280]
__global__ void k_gatectx(const float* __restrict__ context,
                          const float* __restrict__ wgate,
                          const float* __restrict__ bgate,
                          float* __restrict__ gctx) {
    int b = blockIdx.x * blockDim.x + threadIdx.x;
    if (b >= BB) return;
    float acc = bgate[0];
    const float* cb = context + b * ENC;
    for (int e = 0; e < ENC; ++e) acc += cb[e] * wgate[RNN + e];
    gctx[b] = acc;
}

// ---------------- m97-structure tile GEMM core ----------------
// 128x128 WG tile, BK=32, 4 waves of 64x64, global_load_lds(16B) staging,
// 2-barrier K loop. A [M][STRIDE], Bw [N][STRIDE] (row-major, C = A@Bw^T).
template<int STRIDE, int KDIM>
__device__ __forceinline__ void gemm_core(const unsigned short* __restrict__ A,
                                          const unsigned short* __restrict__ Bw,
                                          int mblk, int nblk,
                                          unsigned short* As, unsigned short* Bs,
                                          f32x4 acc[4][4]) {
    const int tid = threadIdx.x, lane = tid & 63, wid = tid >> 6;
    const int wm = (wid >> 1) * 64, wn = (wid & 1) * 64;
    const int lr = lane & 15, lko = (lane >> 4) * 8;
    const int c0 = wid * 128 + lane;          // call 0 chunk for this lane
    const int c1 = c0 + 64;                   // call 1
    const int r0 = c0 >> 2, o0 = (c0 & 3) * 8;
    const int r1 = c1 >> 2, o1 = (c1 & 3) * 8;
    const unsigned short* a0p = A + (size_t)(mblk + r0) * STRIDE + o0;
    const unsigned short* a1p = A + (size_t)(mblk + r1) * STRIDE + o1;
    const unsigned short* b0p = Bw + (size_t)(nblk + r0) * STRIDE + o0;
    const unsigned short* b1p = Bw + (size_t)(nblk + r1) * STRIDE + o1;
    unsigned short* da0 = As + wid * 1024;          // uniform per wave
    unsigned short* da1 = As + wid * 1024 + 512;
    unsigned short* db0 = Bs + wid * 1024;
    unsigned short* db1 = Bs + wid * 1024 + 512;
    for (int k0 = 0; k0 < KDIM; k0 += 32) {
        __syncthreads();   // previous compute done before LDS overwrite
        __builtin_amdgcn_global_load_lds((const GAS unsigned int*)(a0p + k0),
                                         (LAS unsigned int*)da0, 16, 0, 0);
        __builtin_amdgcn_global_load_lds((const GAS unsigned int*)(a1p + k0),
                                         (LAS unsigned int*)da1, 16, 0, 0);
        __builtin_amdgcn_global_load_lds((const GAS unsigned int*)(b0p + k0),
                                         (LAS unsigned int*)db0, 16, 0, 0);
        __builtin_amdgcn_global_load_lds((const GAS unsigned int*)(b1p + k0),
                                         (LAS unsigned int*)db1, 16, 0, 0);
        __syncthreads();   // compiler drains vmcnt before barrier
        bf16x8 af[4], bfv[4];
        #pragma unroll
        for (int mi = 0; mi < 4; ++mi)
            af[mi] = *(const bf16x8*)(As + (wm + mi * 16 + lr) * 32 + lko);
        #pragma unroll
        for (int ni = 0; ni < 4; ++ni)
            bfv[ni] = *(const bf16x8*)(Bs + (wn + ni * 16 + lr) * 32 + lko);
        #pragma unroll
        for (int mi = 0; mi < 4; ++mi)
            #pragma unroll
            for (int ni = 0; ni < 4; ++ni)
                acc[mi][ni] = __builtin_amdgcn_mfma_f32_16x16x32_bf16(
                    af[mi], bfv[ni], acc[mi][ni], 0, 0, 0);
    }
}

// GEMM 1: xproj = frames @ W_ih^T + b_ih + b_hh (bf16 out). M=12800 N=4096 K=1280
__global__ __launch_bounds__(256) void k_gemm_xproj(
    const unsigned short* __restrict__ A,   // [12800][1280]
    const unsigned short* __restrict__ Bw,  // [4096][1280]
    const float* __restrict__ b_ih, const float* __restrict__ b_hh,
    unsigned short* __restrict__ Cout)      // [12800][4096]
{
    __shared__ unsigned short As[4096], Bs[4096];
    f32x4 acc[4][4] = {};
    const int mblk = blockIdx.y * 128, nblk = blockIdx.x * 128;
    gemm_core<INDIM, INDIM>(A, Bw, mblk, nblk, As, Bs, acc);
    const int lane = threadIdx.x & 63, wid = threadIdx.x >> 6;
    const int wm = (wid >> 1) * 64, wn = (wid & 1) * 64, lr = lane & 15;
    #pragma unroll
    for (int ni = 0; ni < 4; ++ni) {
        const int col = nblk + wn + ni * 16 + lr;
        const float bias = b_ih[col] + b_hh[col];
        #pragma unroll
        for (int mi = 0; mi < 4; ++mi) {
            const int row0 = mblk + wm + mi * 16 + (lane >> 4) * 4;
            #pragma unroll
            for (int r = 0; r < 4; ++r)
                Cout[(size_t)(row0 + r) * G4 + col] = f2bf(acc[mi][ni][r] + bias);
        }
    }
}

// GEMM 2: mel = h_all[1:] @ Wp'^T + ctxproj', coalesced scatter via LDS
// transpose. M=12800, N=1280 (permuted col' = mel*16+fr), K=1024.
__global__ __launch_bounds__(256) void k_gemm_mel(
    const unsigned short* __restrict__ A,   // [12800][1024]
    const unsigned short* __restrict__ Bw,  // Wp' [1280][1024] (permuted)
    const float* __restrict__ ctxproj,      // [256][1280] (permuted)
    float* __restrict__ out0)               // [256][80][800]
{
    __shared__ unsigned short As[4096], Bs[4096];
    __shared__ float txp[4][16][20];        // per-wave transpose; 20: align+banks
    f32x4 acc[4][4] = {};
    const int mblk = blockIdx.y * 128, nblk = blockIdx.x * 128;
    gemm_core<RNN, RNN>(A, Bw, mblk, nblk, As, Bs, acc);
    const int lane = threadIdx.x & 63, wid = threadIdx.x >> 6;
    const int wm = (wid >> 1) * 64, wn = (wid & 1) * 64, lr = lane & 15;
    const int rbase = (lane >> 4) * 4;
    const int rowl = lane & 15, fq = lane >> 4;   // readback roles
    #pragma unroll
    for (int mi = 0; mi < 4; ++mi) {
        const int row0 = mblk + wm + mi * 16;     // 16 rows: same t, b0..b0+15
        const int t = row0 >> 8, b0 = row0 & 255;
        #pragma unroll
        for (int ni = 0; ni < 4; ++ni) {
            const int colbase = nblk + wn + ni * 16;  // one mel, fr 0..15
            const int mel = colbase >> 4;
            __syncthreads();                      // txp free for reuse
            #pragma unroll
            for (int r = 0; r < 4; ++r)
                txp[wid][rbase + r][lr] = acc[mi][ni][r];
            __syncthreads();                      // transpose visible
            const int bL = b0 + rowl;
            f32x4 v = *(const f32x4*)&txp[wid][rowl][fq * 4];
            f32x4 cx = *(const f32x4*)(ctxproj + (size_t)bL * INDIM +
                                       mel * 16 + fq * 4);
            *(f32x4*)(out0 + (size_t)(bL * NMEL + mel) * TMEL +
                      t * NFR + fq * 4) = v + cx;
        }
    }
}

// ---------------- persistent recurrence kernel (v6) ----------------
// One launch for all 50 steps. Per-step body = v4's proven all-gload_lds
// structure. Grid 256 = (bx 0..63: n0 = bx*16) x (by 0..3: m0 = by*64);
// 512 thr = 8 waves: wave w -> gate g = w&3, m-half mh = w>>2. c in LDS.
// Cross-step sync: 4 independent 64-WG group barriers (WG (bx,by) only
// needs h rows of its own by-band, produced by WGs (*,by)).
// Round-2 autopsy applied: spin uses RELAXED agent loads (no L2-invalidate
// per poll); release via __ATOMIC_RELEASE fetch_add (one L2 writeback per
// step); NO acquire-invalidate needed: step t reads h slot t — fresh
// addresses, guaranteed local-L2 miss -> fetched from IC where the release
// put them. Whh thus stays L2-resident across all 50 steps.
__global__ __launch_bounds__(512) void k_recur(
    const unsigned short* __restrict__ Whh,    // [4096][1024] bf16
    const unsigned short* __restrict__ xproj,  // [50][256][4096] bf16
    unsigned short* __restrict__ h_all,        // [51][256][1024] bf16
    unsigned int* __restrict__ bar)            // [4*32] zeroed per call
{
    __shared__ unsigned short Asm[2][4096];     // h tile 64r x 64k, dbuf (16KB)
    __shared__ unsigned short Bsm[2][4096];     // Whh 64 vrows x 64k, dbuf (16KB)
    __shared__ float gates[4][64][17];          // 17.4KB, +1 pad
    __shared__ float cst[64][16];               // 4KB cell state (persistent)
    const int tid = threadIdx.x, lane = tid & 63, w = tid >> 6;
    const int g = w & 3, mh = w >> 2;
    const int bx = blockIdx.x & 63, by = blockIdx.x >> 6;
    const int n0 = bx * 16, m0 = by * 64;
    const int lr = lane & 15, q = lane >> 4;

    // staging chunk: cc = w*64+lane; row = cc>>3, 16B-sub = cc&7, XOR-swizzled
    // global source (rule #21 both-sides) + swizzled ds_read below.
    const int cc = w * 64 + lane;
    const int rowc = cc >> 3, s2 = cc & 7;
    const size_t a_off = (size_t)(m0 + rowc) * RNN + ((s2 ^ (rowc & 7)) * 8);
    const unsigned short* bsrc = Whh +
        (size_t)((rowc >> 4) * RNN + n0 + (rowc & 15)) * RNN +
        ((s2 ^ (rowc & 7)) * 8);

    // zero cell state
    for (int i = tid; i < 1024; i += 512) cst[i >> 4][i & 15] = 0.f;

    // ds_read constants
    const int swz_a0 = (mh * 32 + lr) * 64;
    const int swz_a1 = (mh * 32 + 16 + lr) * 64;
    const int swz_b  = (g * 16 + lr) * 64;
    const int sx = lr & 7;
    // phase-0 roles
    const int p0g = tid >> 7, p0row = (tid >> 1) & 63, p0ch = tid & 1;
    // LSTM tail roles
    const int e0 = tid, e1 = tid + 512;

#define STAGE_T(buf, k0) do {                                                  \
    __builtin_amdgcn_global_load_lds((const GAS unsigned int*)(asrc + (k0)),   \
        (LAS unsigned int*)&Asm[buf][w * 512], 16, 0, 0);                      \
    __builtin_amdgcn_global_load_lds((const GAS unsigned int*)(bsrc + (k0)),   \
        (LAS unsigned int*)&Bsm[buf][w * 512], 16, 0, 0); } while (0)

    for (int tt = 0; tt < TT; ++tt) {
        const unsigned short* asrc = h_all + (size_t)tt * BB * RNN + a_off;
        const unsigned short* xp = xproj + (size_t)tt * BB * G4;
        unsigned short* hn = h_all + (size_t)(tt + 1) * BB * RNN;

        STAGE_T(0, 0);
        // phase 0: gates := xproj tile (flies under stage-0)
        {
            bf16x8 xv = *(const bf16x8*)(xp + (size_t)(m0 + p0row) * G4 +
                                         p0g * RNN + n0 + p0ch * 8);
            #pragma unroll
            for (int j = 0; j < 8; ++j)
                gates[p0g][p0row][p0ch * 8 + j] = bf2f((unsigned short)xv[j]);
        }
        __syncthreads();                        // stage-0 drained; cst/gates ok

        f32x4 acc[2] = {};
        #pragma unroll
        for (int it = 0; it < 16; ++it) {
            if (it < 15) STAGE_T((it + 1) & 1, (it + 1) * 64);
            const unsigned short* Ab = Asm[it & 1];
            const unsigned short* Bb = Bsm[it & 1];
            #pragma unroll
            for (int ks = 0; ks < 2; ++ks) {
                const int sub = ks * 4 + q;
                bf16x8 a0 = *(const bf16x8*)(Ab + swz_a0 + ((sub ^ sx) * 8));
                bf16x8 a1 = *(const bf16x8*)(Ab + swz_a1 + ((sub ^ sx) * 8));
                bf16x8 bv = *(const bf16x8*)(Bb + swz_b + ((sub ^ sx) * 8));
                acc[0] = __builtin_amdgcn_mfma_f32_16x16x32_bf16(a0, bv, acc[0], 0, 0, 0);
                acc[1] = __builtin_amdgcn_mfma_f32_16x16x32_bf16(a1, bv, acc[1], 0, 0, 0);
            }
            __syncthreads();   // drains vmcnt (next-tile stage) + lgkm; swap
        }

        // epilogue: accumulate partials into gates (wave-exclusive rows)
        #pragma unroll
        for (int mi = 0; mi < 2; ++mi)
            #pragma unroll
            for (int r = 0; r < 4; ++r)
                gates[g][mh * 32 + mi * 16 + q * 4 + r][lr] += acc[mi][r];
        __syncthreads();

        // LSTM elementwise over 64x16; c stays in LDS; h -> global bf16
        #pragma unroll
        for (int q2 = 0; q2 < 2; ++q2) {
            const int e = q2 ? e1 : e0;
            const int row = e >> 4, col = e & 15;
            const float xi = gates[0][row][col];
            const float xf = gates[1][row][col];
            const float xg = gates[2][row][col];
            const float xo = gates[3][row][col];
            const float si = 1.f / (1.f + expf(-xi));
            const float sf = 1.f / (1.f + expf(-xf));
            const float so = 1.f / (1.f + expf(-xo));
            const float cp = cst[row][col];
            const float cn = sf * cp + si * tanhf(xg);
            const float hnv = so * tanhf(cn);
            cst[row][col] = cn;
            hn[(size_t)(m0 + row) * RNN + n0 + col] = f2bf(hnv);
        }
        __syncthreads();                       // h stores drained (vmcnt0)

        // group barrier: 64 WGs sharing this by-band
        if (tid == 0) {
            // RELEASE: wbl2 once -> h visible at IC for other XCDs
            __hip_atomic_fetch_add(&bar[by * 32], 1u, __ATOMIC_RELEASE,
                                   __HIP_MEMORY_SCOPE_AGENT);
            if (tt < TT - 1) {
                const unsigned tgt = 64u * (unsigned)(tt + 1);
                for (int p = 0; p < (1 << 20); ++p) {   // bounded: no hang
                    unsigned v = __hip_atomic_load(&bar[by * 32],
                                    __ATOMIC_RELAXED, __HIP_MEMORY_SCOPE_AGENT);
                    if (v >= tgt) break;
                    __builtin_amdgcn_s_sleep(8);
                }
            }
        }
        __syncthreads();
    }
#undef STAGE_T
}

// gate[b*50+t] = gatectx[b] + h_all[t+1][b]·w_gate[0:1024] ; one wave per row
__global__ void k_gate(const unsigned short* __restrict__ h,  // [12800][1024]
                       const float* __restrict__ wgate,
                       const float* __restrict__ gctx,
                       float* __restrict__ out1) {
    const int gw = (blockIdx.x * blockDim.x + threadIdx.x) >> 6;
    const int lane = threadIdx.x & 63;
    if (gw >= MROWS) return;
    const unsigned short* hr = h + (size_t)gw * RNN + lane * 16;
    const float* wr = wgate + lane * 16;
    float acc = 0.f;
    #pragma unroll
    for (int j = 0; j < 16; ++j) acc += bf2f(hr[j]) * wr[j];
    for (int off = 32; off; off >>= 1) acc += __shfl_down(acc, off);
    if (lane == 0) {
        const int t = gw >> 8, b = gw & 255;
        out1[b * TT + t] = acc + gctx[b];
    }
}

// ---------------- workspace layout (all offsets 1KB-aligned) ----------------
static const size_t OFF_WIH   = 0;                                    // 10.5 MB
static const size_t OFF_WHH   = OFF_WIH   + (size_t)G4 * INDIM * 2;   // 8 MB
static const size_t OFF_WPH   = OFF_WHH   + (size_t)G4 * RNN * 2;     // 2.6 MB
static const size_t OFF_FRM   = OFF_WPH   + (size_t)INDIM * RNN * 2;  // 32.8 MB
static const size_t OFF_XPROJ = OFF_FRM   + (size_t)MROWS * INDIM * 2;// 104.9 MB
static const size_t OFF_HALL  = OFF_XPROJ + (size_t)MROWS * G4 * 2;   // 26.7 MB
static const size_t OFF_BAR   = OFF_HALL  + (size_t)(TT + 1) * BB * RNN * 2;
static const size_t OFF_CTX   = OFF_BAR   + 1024;
static const size_t OFF_GCTX  = OFF_CTX   + (size_t)BB * INDIM * 4;

extern "C" void kernel_launch(void* const* d_in, const int* in_sizes, int n_in,
                              void* d_out, int out_size, void* d_ws, size_t ws_size,
                              hipStream_t stream) {
    const float* context = (const float*)d_in[0];
    const float* target  = (const float*)d_in[1];
    const float* W_ih    = (const float*)d_in[2];
    const float* b_ih    = (const float*)d_in[3];
    const float* W_hh    = (const float*)d_in[4];
    const float* b_hh    = (const float*)d_in[5];
    const float* W_proj  = (const float*)d_in[6];
    const float* b_proj  = (const float*)d_in[7];
    const float* W_gate  = (const float*)d_in[8];
    const float* b_gate  = (const float*)d_in[9];
    float* out = (float*)d_out;
    char* ws = (char*)d_ws;

    unsigned short* wih_bf  = (unsigned short*)(ws + OFF_WIH);
    unsigned short* whh_bf  = (unsigned short*)(ws + OFF_WHH);
    unsigned short* wph_bf  = (unsigned short*)(ws + OFF_WPH);
    unsigned short* frames  = (unsigned short*)(ws + OFF_FRM);
    unsigned short* xproj   = (unsigned short*)(ws + OFF_XPROJ);
    unsigned short* h_all   = (unsigned short*)(ws + OFF_HALL);
    unsigned int*   bar     = (unsigned int*)(ws + OFF_BAR);
    float*          ctxproj = (float*)(ws + OFF_CTX);
    float*          gctx    = (float*)(ws + OFF_GCTX);

    // per-call init (harness does not re-zero ws between replays)
    hipMemsetAsync(h_all, 0, (size_t)BB * RNN * 2, stream);   // h0 slot
    hipMemsetAsync(bar, 0, 1024, stream);                     // barrier counters

    k_f32_to_bf16<<<2048, 256, 0, stream>>>(W_ih, wih_bf, G4 * INDIM);
    k_f32_to_bf16<<<2048, 256, 0, stream>>>(W_hh, whh_bf, G4 * RNN);
    k_conv_wph<<<2048, 256, 0, stream>>>(W_proj, wph_bf);
    k_frames<<<2048, 256, 0, stream>>>(target, frames);
    k_ctxproj<<<(BB * INDIM + 255) / 256, 256, 0, stream>>>(context, W_proj,
                                                            b_proj, ctxproj);
    k_gatectx<<<1, 256, 0, stream>>>(context, W_gate, b_gate, gctx);

    k_gemm_xproj<<<dim3(G4 / 128, MROWS / 128), 256, 0, stream>>>(
        frames, wih_bf, b_ih, b_hh, xproj);

    k_recur<<<256, 512, 0, stream>>>(whh_bf, xproj, h_all, bar);

    k_gemm_mel<<<dim3(INDIM / 128, MROWS / 128), 256, 0, stream>>>(
        h_all + (size_t)BB * RNN, wph_bf, ctxproj, out);
    k_gate<<<MROWS / 4, 256, 0, stream>>>(h_all + (size_t)BB * RNN, W_gate,
                                          gctx, out + (size_t)BB * NMEL * TMEL);
}

// Round 8
// 1109.298 us; speedup vs baseline: 1.7929x; 1.0915x over previous
//
#include <hip/hip_runtime.h>
#include <hip/hip_bf16.h>
#include <math.h>

// Problem constants
#define BB     256
#define NMEL   80
#define TMEL   800
#define NFR    16          // frames per step
#define TT     50          // decoder steps
#define RNN    1024
#define ENC    256
#define INDIM  1280        // RNN + ENC == MEL_DIM
#define G4     4096        // 4*RNN
#define MROWS  (TT*BB)     // 12800

typedef __attribute__((ext_vector_type(8))) short bf16x8;
typedef __attribute__((ext_vector_type(4))) float f32x4;

#define GAS __attribute__((address_space(1)))
#define LAS __attribute__((address_space(3)))

__device__ __forceinline__ unsigned short f2bf(float f) {
    unsigned int u = __float_as_uint(f);
    u += 0x7FFFu + ((u >> 16) & 1u);     // round-to-nearest-even
    return (unsigned short)(u >> 16);
}
__device__ __forceinline__ float bf2f(unsigned short s) {
    return __uint_as_float(((unsigned int)s) << 16);
}

// ---------------- prep kernels ----------------

__global__ void k_f32_to_bf16(const float* __restrict__ src,
                              unsigned short* __restrict__ dst, int n) {
    for (int i = blockIdx.x * blockDim.x + threadIdx.x; i < n;
         i += gridDim.x * blockDim.x)
        dst[i] = f2bf(src[i]);
}

// W_proj[:, 0:1024] -> bf16, N-permuted: dst row m' = mel*16+fr comes from
// W_proj row m = fr*80+mel. Makes mel-GEMM output contiguous along (t,fr).
__global__ void k_conv_wph(const float* __restrict__ wproj,
                           unsigned short* __restrict__ dst) {
    const int n = INDIM * RNN;
    for (int i = blockIdx.x * blockDim.x + threadIdx.x; i < n;
         i += gridDim.x * blockDim.x) {
        int mp = i >> 10, k = i & 1023;
        int mel = mp >> 4, fr = mp & 15;
        dst[i] = f2bf(wproj[(fr * NMEL + mel) * INDIM + k]);
    }
}

// teacher-forced inputs: frames[t][b][k] = (t==0)?0:target[b][k%80][t*16+k/80]
__global__ void k_frames(const float* __restrict__ target,
                         unsigned short* __restrict__ frames) {
    const int n = TT * BB * INDIM;
    for (int i = blockIdx.x * blockDim.x + threadIdx.x; i < n;
         i += gridDim.x * blockDim.x) {
        int k = i % INDIM;
        int rb = i / INDIM;
        int b = rb & (BB - 1);
        int t = rb >> 8;
        unsigned short v = 0;
        if (t > 0) {
            int mel = k % NMEL, fr = k / NMEL;
            v = f2bf(target[(b * NMEL + mel) * TMEL + t * NFR + fr]);
        }
        frames[i] = v;
    }
}

// ctxproj[b][m'] = b_proj[m] + context[b]·W_proj[m][1024:1280], m'=mel*16+fr,
// m = fr*80+mel (same permutation as k_conv_wph).
__global__ void k_ctxproj(const float* __restrict__ context,
                          const float* __restrict__ wproj,
                          const float* __restrict__ bproj,
                          float* __restrict__ ctx) {
    int i = blockIdx.x * blockDim.x + threadIdx.x;
    if (i >= BB * INDIM) return;
    int mp = i % INDIM, b = i / INDIM;
    int mel = mp >> 4, fr = mp & 15;
    int m = fr * NMEL + mel;
    const float* wr = wproj + (size_t)m * INDIM + RNN;
    const float* cb = context + b * ENC;
    float acc = bproj[m];
    for (int e = 0; e < ENC; ++e) acc += cb[e] * wr[e];
    ctx[(size_t)b * INDIM + mp] = acc;
}

// gatectx[b] = b_gate + context[b]·W_gate[0][1024:1280]
__global__ void k_gatectx(const float* __restrict__ context,
                          const float* __restrict__ wgate,
                          const float* __restrict__ bgate,
                          float* __restrict__ gctx) {
    int b = blockIdx.x * blockDim.x + threadIdx.x;
    if (b >= BB) return;
    float acc = bgate[0];
    const float* cb = context + b * ENC;
    for (int e = 0; e < ENC; ++e) acc += cb[e] * wgate[RNN + e];
    gctx[b] = acc;
}

// ---------------- m97-structure tile GEMM core ----------------
template<int STRIDE, int KDIM>
__device__ __forceinline__ void gemm_core(const unsigned short* __restrict__ A,
                                          const unsigned short* __restrict__ Bw,
                                          int mblk, int nblk,
                                          unsigned short* As, unsigned short* Bs,
                                          f32x4 acc[4][4]) {
    const int tid = threadIdx.x, lane = tid & 63, wid = tid >> 6;
    const int wm = (wid >> 1) * 64, wn = (wid & 1) * 64;
    const int lr = lane & 15, lko = (lane >> 4) * 8;
    const int c0 = wid * 128 + lane;          // call 0 chunk for this lane
    const int c1 = c0 + 64;                   // call 1
    const int r0 = c0 >> 2, o0 = (c0 & 3) * 8;
    const int r1 = c1 >> 2, o1 = (c1 & 3) * 8;
    const unsigned short* a0p = A + (size_t)(mblk + r0) * STRIDE + o0;
    const unsigned short* a1p = A + (size_t)(mblk + r1) * STRIDE + o1;
    const unsigned short* b0p = Bw + (size_t)(nblk + r0) * STRIDE + o0;
    const unsigned short* b1p = Bw + (size_t)(nblk + r1) * STRIDE + o1;
    unsigned short* da0 = As + wid * 1024;          // uniform per wave
    unsigned short* da1 = As + wid * 1024 + 512;
    unsigned short* db0 = Bs + wid * 1024;
    unsigned short* db1 = Bs + wid * 1024 + 512;
    for (int k0 = 0; k0 < KDIM; k0 += 32) {
        __syncthreads();   // previous compute done before LDS overwrite
        __builtin_amdgcn_global_load_lds((const GAS unsigned int*)(a0p + k0),
                                         (LAS unsigned int*)da0, 16, 0, 0);
        __builtin_amdgcn_global_load_lds((const GAS unsigned int*)(a1p + k0),
                                         (LAS unsigned int*)da1, 16, 0, 0);
        __builtin_amdgcn_global_load_lds((const GAS unsigned int*)(b0p + k0),
                                         (LAS unsigned int*)db0, 16, 0, 0);
        __builtin_amdgcn_global_load_lds((const GAS unsigned int*)(b1p + k0),
                                         (LAS unsigned int*)db1, 16, 0, 0);
        __syncthreads();   // compiler drains vmcnt before barrier
        bf16x8 af[4], bfv[4];
        #pragma unroll
        for (int mi = 0; mi < 4; ++mi)
            af[mi] = *(const bf16x8*)(As + (wm + mi * 16 + lr) * 32 + lko);
        #pragma unroll
        for (int ni = 0; ni < 4; ++ni)
            bfv[ni] = *(const bf16x8*)(Bs + (wn + ni * 16 + lr) * 32 + lko);
        #pragma unroll
        for (int mi = 0; mi < 4; ++mi)
            #pragma unroll
            for (int ni = 0; ni < 4; ++ni)
                acc[mi][ni] = __builtin_amdgcn_mfma_f32_16x16x32_bf16(
                    af[mi], bfv[ni], acc[mi][ni], 0, 0, 0);
    }
}

// GEMM 1: xproj = frames @ W_ih^T + b_ih + b_hh (bf16 out). M=12800 N=4096 K=1280
__global__ __launch_bounds__(256) void k_gemm_xproj(
    const unsigned short* __restrict__ A,   // [12800][1280]
    const unsigned short* __restrict__ Bw,  // [4096][1280]
    const float* __restrict__ b_ih, const float* __restrict__ b_hh,
    unsigned short* __restrict__ Cout)      // [12800][4096]
{
    __shared__ unsigned short As[4096], Bs[4096];
    f32x4 acc[4][4] = {};
    const int mblk = blockIdx.y * 128, nblk = blockIdx.x * 128;
    gemm_core<INDIM, INDIM>(A, Bw, mblk, nblk, As, Bs, acc);
    const int lane = threadIdx.x & 63, wid = threadIdx.x >> 6;
    const int wm = (wid >> 1) * 64, wn = (wid & 1) * 64, lr = lane & 15;
    #pragma unroll
    for (int ni = 0; ni < 4; ++ni) {
        const int col = nblk + wn + ni * 16 + lr;
        const float bias = b_ih[col] + b_hh[col];
        #pragma unroll
        for (int mi = 0; mi < 4; ++mi) {
            const int row0 = mblk + wm + mi * 16 + (lane >> 4) * 4;
            #pragma unroll
            for (int r = 0; r < 4; ++r)
                Cout[(size_t)(row0 + r) * G4 + col] = f2bf(acc[mi][ni][r] + bias);
        }
    }
}

// GEMM 2: mel = h_all[1:] @ Wp'^T + ctxproj', coalesced scatter via LDS
// transpose. M=12800, N=1280 (permuted col' = mel*16+fr), K=1024.
__global__ __launch_bounds__(256) void k_gemm_mel(
    const unsigned short* __restrict__ A,   // [12800][1024]
    const unsigned short* __restrict__ Bw,  // Wp' [1280][1024] (permuted)
    const float* __restrict__ ctxproj,      // [256][1280] (permuted)
    float* __restrict__ out0)               // [256][80][800]
{
    __shared__ unsigned short As[4096], Bs[4096];
    __shared__ float txp[4][16][20];        // per-wave transpose; 20: align+banks
    f32x4 acc[4][4] = {};
    const int mblk = blockIdx.y * 128, nblk = blockIdx.x * 128;
    gemm_core<RNN, RNN>(A, Bw, mblk, nblk, As, Bs, acc);
    const int lane = threadIdx.x & 63, wid = threadIdx.x >> 6;
    const int wm = (wid >> 1) * 64, wn = (wid & 1) * 64, lr = lane & 15;
    const int rbase = (lane >> 4) * 4;
    const int rowl = lane & 15, fq = lane >> 4;   // readback roles
    #pragma unroll
    for (int mi = 0; mi < 4; ++mi) {
        const int row0 = mblk + wm + mi * 16;     // 16 rows: same t, b0..b0+15
        const int t = row0 >> 8, b0 = row0 & 255;
        #pragma unroll
        for (int ni = 0; ni < 4; ++ni) {
            const int colbase = nblk + wn + ni * 16;  // one mel, fr 0..15
            const int mel = colbase >> 4;
            __syncthreads();                      // txp free for reuse
            #pragma unroll
            for (int r = 0; r < 4; ++r)
                txp[wid][rbase + r][lr] = acc[mi][ni][r];
            __syncthreads();                      // transpose visible
            const int bL = b0 + rowl;
            f32x4 v = *(const f32x4*)&txp[wid][rowl][fq * 4];
            f32x4 cx = *(const f32x4*)(ctxproj + (size_t)bL * INDIM +
                                       mel * 16 + fq * 4);
            *(f32x4*)(out0 + (size_t)(bL * NMEL + mel) * TMEL +
                      t * NFR + fq * 4) = v + cx;
        }
    }
}

// ---------------- persistent recurrence kernel (v7) ----------------
// Changes vs v6 (792us, latency-serialized):
//  1. 4-deep pipelined K loop: counted s_waitcnt vmcnt(6) + raw s_barrier
//     (vmcnt(0) only at last iter). All staging is global_load_lds — no
//     register global loads anywhere in the loop, so no compiler drains.
//  2. M2 XCD remap: each XCD hosts 2 by-bands x 16 bx-slices
//     (wgid%8 = (by&1)+2*(bx&3)) -> per-XCD h cross-fetch 512->256KB/step,
//     Whh 2MB/XCD L2-resident.
//  3. xproj tile staged via gload_lds into xg dbuf; NEXT step's xg issued
//     BEFORE the band barrier (HBM stream hides under barrier wait).
//     Epilogue computes gates = bf2f(xg) + acc (phase-0 pass deleted).
__global__ __launch_bounds__(512) void k_recur(
    const unsigned short* __restrict__ Whh,    // [4096][1024] bf16
    const unsigned short* __restrict__ xproj,  // [50][256][4096] bf16
    unsigned short* __restrict__ h_all,        // [51][256][1024] bf16
    unsigned int* __restrict__ bar)            // [4*32] zeroed per call
{
    __shared__ unsigned short Asm4[4][4096];    // h tile 64r x 64k, 4-buf (32KB)
    __shared__ unsigned short Bsm4[4][4096];    // Whh 64vr x 64k, 4-buf (32KB)
    __shared__ unsigned short xg[2][4096];      // xproj tile dbuf (16KB)
    __shared__ float gates[4][64][17];          // 17.4KB, +1 pad
    __shared__ float cst[64][16];               // 4KB cell state (persistent)
    const int tid = threadIdx.x, lane = tid & 63, w = tid >> 6;
    const int g = w & 3, mh = w >> 2;
    // M2 remap: XCD x = wgid%8 hosts by in {x&1, (x&1)+2}, bx ≡ (x>>1) mod 4
    const int x = blockIdx.x & 7, rr = blockIdx.x >> 3;
    const int by = (x & 1) + 2 * (rr & 1);
    const int bx = (x >> 1) + 4 * (rr >> 1);
    const int n0 = bx * 16, m0 = by * 64;
    const int lr = lane & 15, q = lane >> 4;

    // staging chunk: cc = w*64+lane; row = cc>>3, 16B-sub = cc&7; XOR-swizzled
    // global source (both-sides rule) matching swizzled ds_read below.
    const int cc = w * 64 + lane;
    const int rowc = cc >> 3, s2 = cc & 7;
    const size_t a_off = (size_t)(m0 + rowc) * RNN + ((s2 ^ (rowc & 7)) * 8);
    const unsigned short* bsrc = Whh +
        (size_t)((rowc >> 4) * RNN + n0 + (rowc & 15)) * RNN +
        ((s2 ^ (rowc & 7)) * 8);
    // xg staging: thread i stages chunk i -> xg layout [4][64][16] row-major
    const size_t xg_off = (size_t)(m0 + ((tid >> 1) & 63)) * G4 +
                          (tid >> 7) * RNN + n0 + (tid & 1) * 8;

    for (int i = tid; i < 1024; i += 512) cst[i >> 4][i & 15] = 0.f;

    const int swz_a0 = (mh * 32 + lr) * 64;
    const int swz_a1 = (mh * 32 + 16 + lr) * 64;
    const int swz_b  = (g * 16 + lr) * 64;
    const int sx = lr & 7;

#define STAGE_T(buf, k0) do {                                                  \
    __builtin_amdgcn_global_load_lds((const GAS unsigned int*)(asrc + (k0)),   \
        (LAS unsigned int*)&Asm4[buf][w * 512], 16, 0, 0);                     \
    __builtin_amdgcn_global_load_lds((const GAS unsigned int*)(bsrc + (k0)),   \
        (LAS unsigned int*)&Bsm4[buf][w * 512], 16, 0, 0); } while (0)

    // xg stage for step 0
    __builtin_amdgcn_global_load_lds((const GAS unsigned int*)(xproj + xg_off),
        (LAS unsigned int*)&xg[0][w * 512], 16, 0, 0);

    for (int tt = 0; tt < TT; ++tt) {
        const unsigned short* asrc = h_all + (size_t)tt * BB * RNN + a_off;
        unsigned short* hn = h_all + (size_t)(tt + 1) * BB * RNN;

        // prologue: fill 3 buffers ahead
        STAGE_T(0, 0); STAGE_T(1, 64); STAGE_T(2, 128);

        f32x4 acc[2] = {};
        #pragma unroll
        for (int it = 0; it < 16; ++it) {
            if (it <= 12) STAGE_T((it + 3) & 3, (it + 3) * 64);
            // wait for stage(it); newer stages (and only they) stay in flight
            if (it <= 12)      asm volatile("s_waitcnt vmcnt(6)" ::: "memory");
            else if (it == 13) asm volatile("s_waitcnt vmcnt(4)" ::: "memory");
            else if (it == 14) asm volatile("s_waitcnt vmcnt(2)" ::: "memory");
            else               asm volatile("s_waitcnt vmcnt(0)" ::: "memory");
            asm volatile("s_barrier" ::: "memory");
            __builtin_amdgcn_sched_barrier(0);
            const unsigned short* Ab = Asm4[it & 3];
            const unsigned short* Bb = Bsm4[it & 3];
            #pragma unroll
            for (int ks = 0; ks < 2; ++ks) {
                const int sub = ks * 4 + q;
                bf16x8 a0 = *(const bf16x8*)(Ab + swz_a0 + ((sub ^ sx) * 8));
                bf16x8 a1 = *(const bf16x8*)(Ab + swz_a1 + ((sub ^ sx) * 8));
                bf16x8 bv = *(const bf16x8*)(Bb + swz_b + ((sub ^ sx) * 8));
                acc[0] = __builtin_amdgcn_mfma_f32_16x16x32_bf16(a0, bv, acc[0], 0, 0, 0);
                acc[1] = __builtin_amdgcn_mfma_f32_16x16x32_bf16(a1, bv, acc[1], 0, 0, 0);
            }
            asm volatile("s_waitcnt lgkmcnt(0)" ::: "memory");
            __builtin_amdgcn_sched_barrier(0);
            asm volatile("s_barrier" ::: "memory");
        }

        // epilogue: gates = xg + acc (wave-exclusive (g,mh) region)
        #pragma unroll
        for (int mi = 0; mi < 2; ++mi)
            #pragma unroll
            for (int r = 0; r < 4; ++r) {
                const int row = mh * 32 + mi * 16 + q * 4 + r;
                gates[g][row][lr] = acc[mi][r] +
                    bf2f(xg[tt & 1][(g * 64 + row) * 16 + lr]);
            }
        __syncthreads();    // nothing outstanding (vmcnt0 at it=15); lgkm drain

        // LSTM tail over 64x16; c stays in LDS; h -> global bf16
        #pragma unroll
        for (int q2 = 0; q2 < 2; ++q2) {
            const int e = tid + q2 * 512;
            const int row = e >> 4, col = e & 15;
            const float xi = gates[0][row][col];
            const float xf = gates[1][row][col];
            const float xgt = gates[2][row][col];
            const float xo = gates[3][row][col];
            const float si = 1.f / (1.f + expf(-xi));
            const float sf = 1.f / (1.f + expf(-xf));
            const float so = 1.f / (1.f + expf(-xo));
            const float cp = cst[row][col];
            const float cn = sf * cp + si * tanhf(xgt);
            const float hnv = so * tanhf(cn);
            cst[row][col] = cn;
            hn[(size_t)(m0 + row) * RNN + n0 + col] = f2bf(hnv);
        }

        if (tt < TT - 1) {
            __builtin_amdgcn_sched_barrier(0);
            // prefetch next step's xproj tile: flies through the barrier wait
            __builtin_amdgcn_global_load_lds(
                (const GAS unsigned int*)(xproj + (size_t)(tt + 1) * BB * G4 + xg_off),
                (LAS unsigned int*)&xg[(tt + 1) & 1][w * 512], 16, 0, 0);
            __builtin_amdgcn_sched_barrier(0);
            // h stores (older than xg) retired; xg may stay in flight
            asm volatile("s_waitcnt vmcnt(1)" ::: "memory");
            asm volatile("s_barrier" ::: "memory");
            if (tid == 0) {
                __hip_atomic_fetch_add(&bar[by * 32], 1u, __ATOMIC_RELEASE,
                                       __HIP_MEMORY_SCOPE_AGENT);
                const unsigned tgt = 64u * (unsigned)(tt + 1);
                for (int p = 0; p < (1 << 20); ++p) {   // bounded: no hang
                    unsigned v = __hip_atomic_load(&bar[by * 32],
                                    __ATOMIC_RELAXED, __HIP_MEMORY_SCOPE_AGENT);
                    if (v >= tgt) break;
                    __builtin_amdgcn_s_sleep(8);
                }
            }
            asm volatile("s_barrier" ::: "memory");
            __builtin_amdgcn_sched_barrier(0);
        }
    }
#undef STAGE_T
}

// gate[b*50+t] = gatectx[b] + h_all[t+1][b]·w_gate[0:1024] ; one wave per row
__global__ void k_gate(const unsigned short* __restrict__ h,  // [12800][1024]
                       const float* __restrict__ wgate,
                       const float* __restrict__ gctx,
                       float* __restrict__ out1) {
    const int gw = (blockIdx.x * blockDim.x + threadIdx.x) >> 6;
    const int lane = threadIdx.x & 63;
    if (gw >= MROWS) return;
    const unsigned short* hr = h + (size_t)gw * RNN + lane * 16;
    const float* wr = wgate + lane * 16;
    float acc = 0.f;
    #pragma unroll
    for (int j = 0; j < 16; ++j) acc += bf2f(hr[j]) * wr[j];
    for (int off = 32; off; off >>= 1) acc += __shfl_down(acc, off);
    if (lane == 0) {
        const int t = gw >> 8, b = gw & 255;
        out1[b * TT + t] = acc + gctx[b];
    }
}

// ---------------- workspace layout (all offsets 1KB-aligned) ----------------
static const size_t OFF_WIH   = 0;                                    // 10.5 MB
static const size_t OFF_WHH   = OFF_WIH   + (size_t)G4 * INDIM * 2;   // 8 MB
static const size_t OFF_WPH   = OFF_WHH   + (size_t)G4 * RNN * 2;     // 2.6 MB
static const size_t OFF_FRM   = OFF_WPH   + (size_t)INDIM * RNN * 2;  // 32.8 MB
static const size_t OFF_XPROJ = OFF_FRM   + (size_t)MROWS * INDIM * 2;// 104.9 MB
static const size_t OFF_HALL  = OFF_XPROJ + (size_t)MROWS * G4 * 2;   // 26.7 MB
static const size_t OFF_BAR   = OFF_HALL  + (size_t)(TT + 1) * BB * RNN * 2;
static const size_t OFF_CTX   = OFF_BAR   + 1024;
static const size_t OFF_GCTX  = OFF_CTX   + (size_t)BB * INDIM * 4;

extern "C" void kernel_launch(void* const* d_in, const int* in_sizes, int n_in,
                              void* d_out, int out_size, void* d_ws, size_t ws_size,
                              hipStream_t stream) {
    const float* context = (const float*)d_in[0];
    const float* target  = (const float*)d_in[1];
    const float* W_ih    = (const float*)d_in[2];
    const float* b_ih    = (const float*)d_in[3];
    const float* W_hh    = (const float*)d_in[4];
    const float* b_hh    = (const float*)d_in[5];
    const float* W_proj  = (const float*)d_in[6];
    const float* b_proj  = (const float*)d_in[7];
    const float* W_gate  = (const float*)d_in[8];
    const float* b_gate  = (const float*)d_in[9];
    float* out = (float*)d_out;
    char* ws = (char*)d_ws;

    unsigned short* wih_bf  = (unsigned short*)(ws + OFF_WIH);
    unsigned short* whh_bf  = (unsigned short*)(ws + OFF_WHH);
    unsigned short* wph_bf  = (unsigned short*)(ws + OFF_WPH);
    unsigned short* frames  = (unsigned short*)(ws + OFF_FRM);
    unsigned short* xproj   = (unsigned short*)(ws + OFF_XPROJ);
    unsigned short* h_all   = (unsigned short*)(ws + OFF_HALL);
    unsigned int*   bar     = (unsigned int*)(ws + OFF_BAR);
    float*          ctxproj = (float*)(ws + OFF_CTX);
    float*          gctx    = (float*)(ws + OFF_GCTX);

    // per-call init (harness does not re-zero ws between replays)
    hipMemsetAsync(h_all, 0, (size_t)BB * RNN * 2, stream);   // h0 slot
    hipMemsetAsync(bar, 0, 1024, stream);                     // barrier counters

    k_f32_to_bf16<<<2048, 256, 0, stream>>>(W_ih, wih_bf, G4 * INDIM);
    k_f32_to_bf16<<<2048, 256, 0, stream>>>(W_hh, whh_bf, G4 * RNN);
    k_conv_wph<<<2048, 256, 0, stream>>>(W_proj, wph_bf);
    k_frames<<<2048, 256, 0, stream>>>(target, frames);
    k_ctxproj<<<(BB * INDIM + 255) / 256, 256, 0, stream>>>(context, W_proj,
                                                            b_proj, ctxproj);
    k_gatectx<<<1, 256, 0, stream>>>(context, W_gate, b_gate, gctx);

    k_gemm_xproj<<<dim3(G4 / 128, MROWS / 128), 256, 0, stream>>>(
        frames, wih_bf, b_ih, b_hh, xproj);

    k_recur<<<256, 512, 0, stream>>>(whh_bf, xproj, h_all, bar);

    k_gemm_mel<<<dim3(INDIM / 128, MROWS / 128), 256, 0, stream>>>(
        h_all + (size_t)BB * RNN, wph_bf, ctxproj, out);
    k_gate<<<MROWS / 4, 256, 0, stream>>>(h_all + (size_t)BB * RNN, W_gate,
                                          gctx, out + (size_t)BB * NMEL * TMEL);
}